// Round 11
// baseline (171.804 us; speedup 1.0000x reference)
//
#include <hip/hip_runtime.h>
#include <math.h>

#define N_PTS 65536
#define M_IND 1024
#define KNN 16
#define JITTER 1e-4f

// Packed lower-triangular Su: P[i*(i+1)/2 + j], j <= i.
#define PACKED_FLOATS (M_IND * (M_IND + 1) / 2)               // 524800
#define PACKED_BYTES  ((size_t)PACKED_FLOATS * sizeof(float)) // 2,099,200 B

#define TSU 32
#define SU_BLOCKS 528          // 32*33/2 triangular tiles
#define NCHUNKS 5984           // sum over tiles of (ct+1) k-chunks
#define PTS_PER_BLK 128        // 512 blocks, 2/CU resident
#define QSTRIDE 17             // u64 per point row (136 B)
#define GRID_BLKS (N_PTS / PTS_PER_BLK)   // 512
#define SPIN_MAX 32768         // ~5 ms bound; then exact Lu fallback

// R21 ledger:
//  - ATTRIBUTION CORRECTED (R13/R18/R20 joint solve): sel ~30us, p2 ~62-65us
//    (reg-A and LDS-A variants EQUAL — R18's gain was removing su, not LDS-A),
//    su-in-kernel ~+19us on the crit chain (worst block owns the rt=31 tile:
//    32 serial chunks ~20us; mean is only 11.7 chunks).
//  - R21: balanced su — all 5984 k-chunks flattened over 512 blocks (11-12
//    each); partial tile products accumulate via atomicAdd into memset-zeroed
//    P. Crit-path su 20 -> ~8us. Bounded spin + flag fallback retained.
//  - LDS 70160 B/block -> 2 blocks/CU with 23.5 KiB slack (proven regime).
//  - Spill tripwire: WRITE_SIZE (kernel) should stay <10 MB.

// ---------------------------------------------------------------------------
// One 32x32 Su tile (packed tril(Lu Lu^T)). As/Bs are LDS scratch.
// (Per-tile version: standalone su_kernel / MODE 1 fallback only.)
// ---------------------------------------------------------------------------
__device__ __forceinline__ void su_tile(const float* __restrict__ Lu_raw,
                                        float* __restrict__ P,
                                        int bid, int tid,
                                        float (*As)[36], float (*Bs)[36]) {
    int rt = (int)((sqrtf(8.0f * (float)bid + 1.0f) - 1.0f) * 0.5f);
    while ((rt + 1) * (rt + 2) / 2 <= bid) ++rt;
    while (rt * (rt + 1) / 2 > bid) --rt;
    int ct = bid - rt * (rt + 1) / 2;   // ct <= rt
    int i0 = rt * TSU, j0 = ct * TSU;

    int tx = tid & 15, ty = tid >> 4;
    int sr = tid >> 3, sc = (tid & 7) << 2;
    float a00 = 0.f, a01 = 0.f, a10 = 0.f, a11 = 0.f;

    int nch = ct + 1;                      // k-chunks of 32 (k <= j0+31)
    int gi = i0 + sr, gj = j0 + sr;
    float4 pa = *(const float4*)(Lu_raw + (unsigned)gi * M_IND + sc);
    float4 pb = *(const float4*)(Lu_raw + (unsigned)gj * M_IND + sc);

    for (int c = 0; c < nch; ++c) {
        int gk = (c << 5) + sc;
        float aa[4] = {pa.x, pa.y, pa.z, pa.w};
        float bb[4] = {pb.x, pb.y, pb.z, pb.w};
        #pragma unroll
        for (int q = 0; q < 4; ++q) {
            int k = gk + q;
            aa[q] = (k < gi) ? aa[q] : ((k == gi) ? __expf(aa[q]) : 0.0f);
            bb[q] = (k < gj) ? bb[q] : ((k == gj) ? __expf(bb[q]) : 0.0f);
        }
        *(float4*)&As[sr][sc] = make_float4(aa[0], aa[1], aa[2], aa[3]);
        *(float4*)&Bs[sr][sc] = make_float4(bb[0], bb[1], bb[2], bb[3]);
        __syncthreads();
        if (c + 1 < nch) {
            int kn = ((c + 1) << 5) + sc;
            pa = *(const float4*)(Lu_raw + (unsigned)gi * M_IND + kn);
            pb = *(const float4*)(Lu_raw + (unsigned)gj * M_IND + kn);
        }
        #pragma unroll
        for (int kk = 0; kk < 32; kk += 4) {
            float4 av0 = *(const float4*)&As[ty][kk];
            float4 av1 = *(const float4*)&As[ty + 16][kk];
            float4 bv0 = *(const float4*)&Bs[tx][kk];
            float4 bv1 = *(const float4*)&Bs[tx + 16][kk];
            a00 = fmaf(av0.x, bv0.x, fmaf(av0.y, bv0.y, fmaf(av0.z, bv0.z, fmaf(av0.w, bv0.w, a00))));
            a01 = fmaf(av0.x, bv1.x, fmaf(av0.y, bv1.y, fmaf(av0.z, bv1.z, fmaf(av0.w, bv1.w, a01))));
            a10 = fmaf(av1.x, bv0.x, fmaf(av1.y, bv0.y, fmaf(av1.z, bv0.z, fmaf(av1.w, bv0.w, a10))));
            a11 = fmaf(av1.x, bv1.x, fmaf(av1.y, bv1.y, fmaf(av1.z, bv1.z, fmaf(av1.w, bv1.w, a11))));
        }
        __syncthreads();
    }

    int ia = i0 + ty, ib = i0 + ty + 16;
    int ja = j0 + tx, jb = j0 + tx + 16;
    if (ja <= ia) P[((unsigned)ia * (ia + 1) >> 1) + ja] = a00;
    if (jb <= ia) P[((unsigned)ia * (ia + 1) >> 1) + jb] = a01;
    if (ja <= ib) P[((unsigned)ib * (ib + 1) >> 1) + ja] = a10;
    if (jb <= ib) P[((unsigned)ib * (ib + 1) >> 1) + jb] = a11;
}

// Standalone su kernel (MODE 1 fallback path only).
__global__ __launch_bounds__(256) void su_kernel(const float* __restrict__ Lu_raw,
                                                 float* __restrict__ P) {
    __shared__ float As[TSU][36];
    __shared__ float Bs[TSU][36];
    su_tile(Lu_raw, P, blockIdx.x, threadIdx.x, As, Bs);
}

// ---------------------------------------------------------------------------
// Sorting-network helpers.
// ---------------------------------------------------------------------------
__device__ __forceinline__ void ce(unsigned long long& x, unsigned long long& y) {
    unsigned long long a = x, b = y;
    bool c = a < b;
    x = c ? a : b;
    y = c ? b : a;
}
__device__ __forceinline__ void ce(float& x, float& y) {
    float a = fminf(x, y), b = fmaxf(x, y);
    x = a; y = b;
}

template <typename KT>
__device__ __forceinline__ void sort16(KT* a) {
    #pragma unroll
    for (int p = 1; p < 16; p <<= 1)
        #pragma unroll
        for (int k = p; k >= 1; k >>= 1)
            #pragma unroll
            for (int j = k & (p - 1); j + k < 16; j += 2 * k)
                #pragma unroll
                for (int i = 0; i < k; ++i)
                    if (i + j + k < 16)
                        if (((i + j) / (2 * p)) == ((i + j + k) / (2 * p)))
                            ce(a[i + j], a[i + j + k]);
}

template <typename KT>
__device__ __forceinline__ void cleanup16(KT* a) {
    #pragma unroll
    for (int d = 8; d >= 1; d >>= 1)
        #pragma unroll
        for (int i = 0; i < 16; ++i)
            if ((i & d) == 0) ce(a[i], a[i | d]);
}

// u-space distance surrogate: u = 0.5*|z|^2 - x.z  (Zs.w holds 0.5*|z|^2).
// d = max(2u + xq, 0) is monotone in u.
__device__ __forceinline__ float uval(float4 z, float xn0, float xn1, float xn2) {
    return fmaf(xn0, z.x, fmaf(xn1, z.y, fmaf(xn2, z.z, z.w)));
}

// ---------------------------------------------------------------------------
// MODE 2: fused (balanced su chunks + bounded ctr spin, spin placed LATE).
// MODE 1: P from su_kernel. MODE 0: no-workspace exact fallback.
// 512 blocks x 256 thr, 128 pts/blk. Selection: R13-proven (4 subs x 2 pts).
// Phase 2: serial per-thread (tid<128) with A in LDS (R18/R20-proven).
// LDS map: Zs [0,16384) | mus [16384,20480) | qb [20480,37888) |
//          su As/Bs [20480,29696) (MODE 2, dead before A) |
//          A [0,70144) = 128 pts x 137 dwords (overlays EVERYTHING after the
//          barriered entry reads; all prior contents reg-cached) |
//          flag [70144,70148).
// Block LDS 70160 B -> 2 blocks/CU with 23.5 KiB slack (proven regime).
// ---------------------------------------------------------------------------
template <int MODE>
__global__ __launch_bounds__(256, 2) void vnngp_kernel(const float* __restrict__ X,
                                                       const float* __restrict__ Z,
                                                       const float* __restrict__ mu,
                                                       float* __restrict__ P,
                                                       const float* __restrict__ Lu_raw,
                                                       unsigned int* __restrict__ ctr,
                                                       float* __restrict__ out) {
    __shared__ __align__(16) char smem[70160];
    float4* Zs = (float4*)smem;                                  // 16 KB
    float* mus = (float*)(smem + 16384);                         // 4 KB
    unsigned long long* qb = (unsigned long long*)(smem + 20480); // 17 KB
    int* flagp = (int*)(smem + 70144);
    int tid = threadIdx.x;

    for (int r = tid; r < M_IND; r += 256) {
        float zx = Z[r * 3 + 0], zy = Z[r * 3 + 1], zz = Z[r * 3 + 2];
        Zs[r] = make_float4(zx, zy, zz, 0.5f * (zx * zx + zy * zy + zz * zz));
        mus[r] = mu[r];
    }

    if (MODE == 2) {
        // Balanced su: NCHUNKS k-chunks flattened across the 512 blocks
        // (11-12 each, vs 32 on the old worst block); partial tile products
        // accumulate via atomicAdd into memset-zeroed P.
        float (*As)[36] = (float (*)[36])(smem + 20480);
        float (*Bs)[36] = (float (*)[36])(smem + 20480 + 4608);
        int s = (int)(((unsigned)blockIdx.x * NCHUNKS) >> 9);
        int e = (int)((((unsigned)blockIdx.x + 1u) * NCHUNKS) >> 9);
        // Decode flat chunk id s -> (rt, ct, c). Row rt holds
        // (rt+1)(rt+2)/2 chunks; tile (rt,ct) holds ct+1 chunks.
        int rt = 0, rem = s;
        while (rem >= ((rt + 1) * (rt + 2)) >> 1) {
            rem -= ((rt + 1) * (rt + 2)) >> 1;
            ++rt;
        }
        int ct = 0;
        while (rem > ct) { rem -= (ct + 1); ++ct; }
        int c = rem;

        int tx = tid & 15, ty = tid >> 4;
        int sr = tid >> 3, sc = (tid & 7) << 2;
        int i0 = rt * TSU, j0 = ct * TSU;
        int gi = i0 + sr, gj = j0 + sr;
        float a00 = 0.f, a01 = 0.f, a10 = 0.f, a11 = 0.f;
        int dirty = 0;

        for (int q = s; q < e; ++q) {
            int gk = (c << 5) + sc;
            float4 pa = *(const float4*)(Lu_raw + (unsigned)gi * M_IND + gk);
            float4 pb = *(const float4*)(Lu_raw + (unsigned)gj * M_IND + gk);
            float aa[4] = {pa.x, pa.y, pa.z, pa.w};
            float bb[4] = {pb.x, pb.y, pb.z, pb.w};
            #pragma unroll
            for (int qq = 0; qq < 4; ++qq) {
                int k = gk + qq;
                aa[qq] = (k < gi) ? aa[qq] : ((k == gi) ? __expf(aa[qq]) : 0.0f);
                bb[qq] = (k < gj) ? bb[qq] : ((k == gj) ? __expf(bb[qq]) : 0.0f);
            }
            __syncthreads();               // prior chunk's FMA reads done
            *(float4*)&As[sr][sc] = make_float4(aa[0], aa[1], aa[2], aa[3]);
            *(float4*)&Bs[sr][sc] = make_float4(bb[0], bb[1], bb[2], bb[3]);
            __syncthreads();
            #pragma unroll
            for (int kk = 0; kk < 32; kk += 4) {
                float4 av0 = *(const float4*)&As[ty][kk];
                float4 av1 = *(const float4*)&As[ty + 16][kk];
                float4 bv0 = *(const float4*)&Bs[tx][kk];
                float4 bv1 = *(const float4*)&Bs[tx + 16][kk];
                a00 = fmaf(av0.x, bv0.x, fmaf(av0.y, bv0.y, fmaf(av0.z, bv0.z, fmaf(av0.w, bv0.w, a00))));
                a01 = fmaf(av0.x, bv1.x, fmaf(av0.y, bv1.y, fmaf(av0.z, bv1.z, fmaf(av0.w, bv1.w, a01))));
                a10 = fmaf(av1.x, bv0.x, fmaf(av1.y, bv0.y, fmaf(av1.z, bv0.z, fmaf(av1.w, bv0.w, a10))));
                a11 = fmaf(av1.x, bv1.x, fmaf(av1.y, bv1.y, fmaf(av1.z, bv1.z, fmaf(av1.w, bv1.w, a11))));
            }
            dirty = 1;
            ++c;
            if (c > ct) {                  // finished tile (rt,ct): flush
                int ia = i0 + ty, ib = i0 + ty + 16;
                int ja = j0 + tx, jb = j0 + tx + 16;
                if (ja <= ia) atomicAdd(&P[((unsigned)ia * (ia + 1) >> 1) + ja], a00);
                if (jb <= ia) atomicAdd(&P[((unsigned)ia * (ia + 1) >> 1) + jb], a01);
                if (ja <= ib) atomicAdd(&P[((unsigned)ib * (ib + 1) >> 1) + ja], a10);
                if (jb <= ib) atomicAdd(&P[((unsigned)ib * (ib + 1) >> 1) + jb], a11);
                a00 = a01 = a10 = a11 = 0.f;
                dirty = 0;
                c = 0; ++ct;
                if (ct > rt) { ct = 0; ++rt; }
                i0 = rt * TSU; j0 = ct * TSU;
                gi = i0 + sr; gj = j0 + sr;
            }
        }
        if (dirty) {                       // partial tail tile
            int ia = i0 + ty, ib = i0 + ty + 16;
            int ja = j0 + tx, jb = j0 + tx + 16;
            if (ja <= ia) atomicAdd(&P[((unsigned)ia * (ia + 1) >> 1) + ja], a00);
            if (jb <= ia) atomicAdd(&P[((unsigned)ia * (ia + 1) >> 1) + jb], a01);
            if (ja <= ib) atomicAdd(&P[((unsigned)ib * (ib + 1) >> 1) + ja], a10);
            if (jb <= ib) atomicAdd(&P[((unsigned)ib * (ib + 1) >> 1) + jb], a11);
        }
        __syncthreads();                   // As/Bs reads done before qb reuse
        if (tid == 0) {
            __threadfence();               // device-scope release of P atomics
            atomicAdd(ctr, 1u);
        }
    } else {
        __syncthreads();
    }

    {
        int pt = tid >> 2, sub = tid & 3;     // pt 0..63, quad handles pt & pt+64
        int nA = blockIdx.x * PTS_PER_BLK + pt;
        int nB = nA + 64;
        float xA0 = X[nA * 3 + 0], xA1 = X[nA * 3 + 1], xA2 = X[nA * 3 + 2];
        float xB0 = X[nB * 3 + 0], xB1 = X[nB * 3 + 1], xB2 = X[nB * 3 + 2];
        float xqA = fmaf(xA0, xA0, fmaf(xA1, xA1, xA2 * xA2));
        float xqB = fmaf(xB0, xB0, fmaf(xB1, xB1, xB2 * xB2));
        float nA0 = -xA0, nA1 = -xA1, nA2 = -xA2;
        float nB0 = -xB0, nB1 = -xB1, nB2 = -xB2;
        int mbase = sub << 8;
        int rot = sub << 1;   // subs land on disjoint bank quads

        // ---- Pass 1: 16 interleaved class minima per point (u-space) ----
        float TA[16], TB[16];
        #pragma unroll
        for (int j = 0; j < 16; ++j) { TA[j] = 3.4e38f; TB[j] = 3.4e38f; }
        #pragma unroll 1
        for (int c = 0; c < 16; ++c) {
            int base = mbase + (c << 4);
            #pragma unroll
            for (int j = 0; j < 16; ++j) {
                int m = base + ((j + rot) & 15);
                float4 z = Zs[m];
                TA[j] = fminf(TA[j], uval(z, nA0, nA1, nA2));
                TB[j] = fminf(TB[j], uval(z, nB0, nB1, nB2));
            }
        }
        sort16(TA);
        sort16(TB);
        #pragma unroll
        for (int round = 1; round <= 2; round <<= 1) {
            float oA[16], oB[16];
            #pragma unroll
            for (int i = 0; i < 16; ++i) {
                oA[i] = __shfl_xor(TA[i], round, 64);
                oB[i] = __shfl_xor(TB[i], round, 64);
            }
            #pragma unroll
            for (int i = 0; i < 16; ++i) {
                TA[i] = fminf(TA[i], oA[15 - i]);
                TB[i] = fminf(TB[i], oB[15 - i]);
            }
            cleanup16(TA);
            cleanup16(TB);
        }
        float TstarA = TA[15], TstarB = TB[15];   // u-space thresholds

        // ---- Pass 2: collect indices with u <= Tstar (u16, cap 16/sub) ----
        unsigned short* mycA = ((unsigned short*)qb) + pt * (QSTRIDE * 4) + sub * 16;
        unsigned short* mycB = ((unsigned short*)qb) + (pt + 64) * (QSTRIDE * 4) + sub * 16;
        int cntA = 0, cntB = 0;
        #pragma unroll 1
        for (int c = 0; c < 16; ++c) {
            int base = mbase + (c << 4);
            #pragma unroll
            for (int j = 0; j < 16; ++j) {
                int m = base + ((j + rot) & 15);
                float4 z = Zs[m];
                float uA = uval(z, nA0, nA1, nA2);
                float uB = uval(z, nB0, nB1, nB2);
                if (uA <= TstarA) { if (cntA < 16) mycA[cntA] = (unsigned short)m; ++cntA; }
                if (uB <= TstarB) { if (cntB < 16) mycB[cntB] = (unsigned short)m; ++cntB; }
            }
        }

        int ovfA = cntA > 16 ? 1 : 0;
        ovfA |= __shfl_xor(ovfA, 1, 64);
        ovfA |= __shfl_xor(ovfA, 2, 64);
        int ovfB = cntB > 16 ? 1 : 0;
        ovfB |= __shfl_xor(ovfB, 1, 64);
        ovfB |= __shfl_xor(ovfB, 2, 64);

        // ---- finalize point A ----
        if (!ovfA) {
            const unsigned long long* m64 = (const unsigned long long*)mycA;
            unsigned long long raw[4] = {m64[0], m64[1], m64[2], m64[3]};
            unsigned long long C[16];
            #pragma unroll
            for (int i = 0; i < 16; ++i) {
                int m = (int)((raw[i >> 2] >> ((i & 3) * 16)) & 0x3FF);
                float u = uval(Zs[m], nA0, nA1, nA2);
                float d = fmaxf(fmaf(2.0f, u, xqA), 0.0f);
                unsigned long long key =
                    ((unsigned long long)__float_as_uint(d) << 32) | (unsigned)m;
                C[i] = (i < cntA) ? key : ~0ULL;
            }
            sort16(C);
            #pragma unroll
            for (int round = 1; round <= 2; round <<= 1) {
                unsigned long long o[16];
                #pragma unroll
                for (int i = 0; i < 16; ++i) o[i] = __shfl_xor(C[i], round, 64);
                #pragma unroll
                for (int i = 0; i < 16; ++i) {
                    unsigned long long b = o[15 - i];
                    C[i] = C[i] < b ? C[i] : b;
                }
                cleanup16(C);
            }
            if (sub == 0) {
                #pragma unroll
                for (int i = 0; i < 16; ++i) qb[pt * QSTRIDE + i] = C[i];
            }
        } else if (sub == 0) {
            unsigned long long R[16];
            #pragma unroll
            for (int i = 0; i < 16; ++i) R[i] = ~0ULL;
            for (int m = 0; m < M_IND; ++m) {
                float u = uval(Zs[m], nA0, nA1, nA2);
                float d = fmaxf(fmaf(2.0f, u, xqA), 0.0f);
                unsigned long long kk =
                    ((unsigned long long)__float_as_uint(d) << 32) | (unsigned)m;
                if (kk < R[15]) {
                    #pragma unroll
                    for (int j = 0; j < 16; ++j) {
                        unsigned long long t = R[j];
                        bool cc = kk < t;
                        R[j] = cc ? kk : t;
                        kk = cc ? t : kk;
                    }
                }
            }
            #pragma unroll
            for (int i = 0; i < 16; ++i) qb[pt * QSTRIDE + i] = R[i];
        }

        // ---- finalize point B ----
        if (!ovfB) {
            const unsigned long long* m64 = (const unsigned long long*)mycB;
            unsigned long long raw[4] = {m64[0], m64[1], m64[2], m64[3]};
            unsigned long long C[16];
            #pragma unroll
            for (int i = 0; i < 16; ++i) {
                int m = (int)((raw[i >> 2] >> ((i & 3) * 16)) & 0x3FF);
                float u = uval(Zs[m], nB0, nB1, nB2);
                float d = fmaxf(fmaf(2.0f, u, xqB), 0.0f);
                unsigned long long key =
                    ((unsigned long long)__float_as_uint(d) << 32) | (unsigned)m;
                C[i] = (i < cntB) ? key : ~0ULL;
            }
            sort16(C);
            #pragma unroll
            for (int round = 1; round <= 2; round <<= 1) {
                unsigned long long o[16];
                #pragma unroll
                for (int i = 0; i < 16; ++i) o[i] = __shfl_xor(C[i], round, 64);
                #pragma unroll
                for (int i = 0; i < 16; ++i) {
                    unsigned long long b = o[15 - i];
                    C[i] = C[i] < b ? C[i] : b;
                }
                cleanup16(C);
            }
            if (sub == 0) {
                #pragma unroll
                for (int i = 0; i < 16; ++i) qb[(pt + 64) * QSTRIDE + i] = C[i];
            }
        } else if (sub == 0) {
            unsigned long long R[16];
            #pragma unroll
            for (int i = 0; i < 16; ++i) R[i] = ~0ULL;
            for (int m = 0; m < M_IND; ++m) {
                float u = uval(Zs[m], nB0, nB1, nB2);
                float d = fmaxf(fmaf(2.0f, u, xqB), 0.0f);
                unsigned long long kk =
                    ((unsigned long long)__float_as_uint(d) << 32) | (unsigned)m;
                if (kk < R[15]) {
                    #pragma unroll
                    for (int j = 0; j < 16; ++j) {
                        unsigned long long t = R[j];
                        bool cc = kk < t;
                        R[j] = cc ? kk : t;
                        kk = cc ? t : kk;
                    }
                }
            }
            #pragma unroll
            for (int i = 0; i < 16; ++i) qb[(pt + 64) * QSTRIDE + i] = R[i];
        }
    }
    __syncthreads();

    // ---- Phase 2 entry reads (before the A region clobbers Zs/mus/qb) ----
    int idx[KNN];
    float kv[KNN], musr[KNN];
    float nx[KNN], ny[KNN], nz[KNN], nq[KNN];
    if (tid < PTS_PER_BLK) {
        #pragma unroll
        for (int a = 0; a < KNN; ++a) {
            unsigned long long k = qb[tid * QSTRIDE + a];
            int ia = (int)(k & 0xFFFFFFFFULL);
            float d = __uint_as_float((unsigned)(k >> 32));
            idx[a] = ia;
            kv[a] = __expf(-0.5f * d);            // lKxz entries
            float4 z = Zs[ia];
            nx[a] = z.x; ny[a] = z.y; nz[a] = z.z; nq[a] = z.w; // nq = 0.5|z|^2
            musr[a] = mus[ia];
        }
    }
    __syncthreads();   // ALL threads; entry reads drained before A writes

    // ---- Phase 2 part 1 (P-independent): A-build, Cholesky, solves ----
    float* Ab = (float*)smem + tid * 137;
    float w[KNN];
    float wk = 0.f, ww = 0.f, mean = 0.f;
    if (tid < PTS_PER_BLK) {
        // A = lKzz + JITTER*I (lower tri); diag = 1 + 2*JITTER.
        #pragma unroll
        for (int r = 0; r < KNN; ++r) {
            Ab[r * (r + 1) / 2 + r] = 1.0f + 2.0f * JITTER;
            #pragma unroll
            for (int c = 0; c < r; ++c) {
                float dot = fmaf(nx[r], nx[c], fmaf(ny[r], ny[c], nz[r] * nz[c]));
                Ab[r * (r + 1) / 2 + c] = __expf(fminf(dot - nq[r] - nq[c], 0.0f));
            }
        }

        // In-place Cholesky; 1/L[c][c] stored on the diagonal (rsqrt).
        #pragma unroll
        for (int c = 0; c < KNN; ++c) {
            float diag = Ab[c * (c + 1) / 2 + c];
            #pragma unroll
            for (int k = 0; k < c; ++k) {
                float lv = Ab[c * (c + 1) / 2 + k];
                diag = fmaf(-lv, lv, diag);
            }
            float rinv = __frsqrt_rn(fmaxf(diag, 1e-12f));
            Ab[c * (c + 1) / 2 + c] = rinv;
            #pragma unroll
            for (int r = c + 1; r < KNN; ++r) {
                float v = Ab[r * (r + 1) / 2 + c];
                #pragma unroll
                for (int k = 0; k < c; ++k)
                    v = fmaf(-Ab[r * (r + 1) / 2 + k], Ab[c * (c + 1) / 2 + k], v);
                Ab[r * (r + 1) / 2 + c] = v * rinv;
            }
        }

        // Solve A w = kv (forward then backward).
        #pragma unroll
        for (int r = 0; r < KNN; ++r) {
            float v = kv[r];
            #pragma unroll
            for (int c = 0; c < r; ++c) v = fmaf(-Ab[r * (r + 1) / 2 + c], w[c], v);
            w[r] = v * Ab[r * (r + 1) / 2 + r];
        }
        #pragma unroll
        for (int r = KNN - 1; r >= 0; --r) {
            float v = w[r];
            #pragma unroll
            for (int c = r + 1; c < KNN; ++c) v = fmaf(-Ab[c * (c + 1) / 2 + r], w[c], v);
            w[r] = v * Ab[r * (r + 1) / 2 + r];
        }

        // W lKzz W^T = w.k - JITTER*||w||^2   (A w = k, lKzz = A - JITTER*I)
        #pragma unroll
        for (int a = 0; a < KNN; ++a) {
            wk = fmaf(w[a], kv[a], wk);
            ww = fmaf(w[a], w[a], ww);
            mean = fmaf(w[a], musr[a], mean);
        }
    }

    bool havP = (MODE == 1);
    if (MODE == 2) {
        // LATE bounded spin: all P-independent work done; balanced su
        // (~8us) finished long before this point. On timeout, fall back
        // to the exact Lu path below (slow-correct, never a hang).
        if (tid == 0) {
            int ok = 1, iters = 0;
            while (__hip_atomic_load(ctr, __ATOMIC_ACQUIRE, __HIP_MEMORY_SCOPE_AGENT)
                   < (unsigned)GRID_BLKS) {
                __builtin_amdgcn_s_sleep(8);
                if (++iters > SPIN_MAX) { ok = 0; break; }
            }
            *flagp = ok;
        }
        __syncthreads();
        havP = (*flagp != 0);
    }
    if (tid >= PTS_PER_BLK) return;

    // ---- qs = w^T Su[idx,idx] w ----
    float qs = 0.f;
    if (MODE != 0 && havP) {
        #pragma unroll
        for (int r = 0; r < KNN; ++r) {
            int a = idx[r];
            float wr = w[r];
            float rowacc = 0.f;
            #pragma unroll
            for (int c = 0; c < r; ++c) {
                int b = idx[c];
                int hi = a > b ? a : b;
                int lo = a > b ? b : a;
                rowacc = fmaf(w[c], P[((unsigned)hi * (hi + 1) >> 1) + lo], rowacc);
            }
            qs = fmaf(wr, fmaf(wr, P[((unsigned)a * (a + 1) >> 1) + a], 2.0f * rowacc), qs);
        }
    } else {
        // Exact on-demand: qs = sum_k (sum_a w_a * Lu[idx_a, k])^2
        int si[KNN]; float sw[KNN];
        #pragma unroll
        for (int a = 0; a < KNN; ++a) { si[a] = idx[a]; sw[a] = w[a]; }
        #pragma unroll
        for (int a = 1; a < KNN; ++a) {
            int iv = si[a]; float wv = sw[a];
            int b = a - 1;
            while (b >= 0 && si[b] > iv) { si[b + 1] = si[b]; sw[b + 1] = sw[b]; --b; }
            si[b + 1] = iv; sw[b + 1] = wv;
        }
        int s = 0;
        int kend = si[KNN - 1];
        for (int k = 0; k <= kend; ++k) {
            float v = 0.f;
            if (s < KNN && si[s] == k) {
                v = sw[s] * __expf(Lu_raw[(unsigned)k * M_IND + k]);
                ++s;
            }
            for (int a = s; a < KNN; ++a)
                v = fmaf(sw[a], Lu_raw[(unsigned)si[a] * M_IND + k], v);
            qs = fmaf(v, v, qs);
        }
    }

    int n = blockIdx.x * PTS_PER_BLK + tid;
    float cov = 1.0f - (wk - JITTER * ww) + qs;
    float sd = sqrtf(fmaxf(cov, 0.05f));
    out[n] = mean;
    out[N_PTS + n] = sd;
}

// ---------------------------------------------------------------------------
extern "C" void kernel_launch(void* const* d_in, const int* in_sizes, int n_in,
                              void* d_out, int out_size, void* d_ws, size_t ws_size,
                              hipStream_t stream) {
    const float* X      = (const float*)d_in[0];
    const float* Z      = (const float*)d_in[1];
    const float* Lu_raw = (const float*)d_in[2];
    const float* mu     = (const float*)d_in[3];
    float* out = (float*)d_out;

    if (ws_size >= PACKED_BYTES + 64) {
        // Fused: P (atomic-accumulated, so zeroed) + counter live in d_ws.
        float* P = (float*)d_ws;
        unsigned int* ctr = (unsigned int*)((char*)d_ws + PACKED_BYTES);
        hipMemsetAsync(P, 0, PACKED_BYTES, stream);
        hipMemsetAsync(ctr, 0, sizeof(unsigned int), stream);
        vnngp_kernel<2><<<GRID_BLKS, 256, 0, stream>>>(X, Z, mu, P, Lu_raw, ctr, out);
    } else if (ws_size >= PACKED_BYTES) {
        float* P = (float*)d_ws;
        su_kernel<<<SU_BLOCKS, 256, 0, stream>>>(Lu_raw, P);
        vnngp_kernel<1><<<GRID_BLKS, 256, 0, stream>>>(X, Z, mu, P, Lu_raw, nullptr, out);
    } else {
        vnngp_kernel<0><<<GRID_BLKS, 256, 0, stream>>>(X, Z, mu, nullptr, Lu_raw, nullptr, out);
    }
}

// Round 12
// 164.799 us; speedup vs baseline: 1.0425x; 1.0425x over previous
//
#include <hip/hip_runtime.h>
#include <math.h>

#define N_PTS 65536
#define M_IND 1024
#define KNN 16
#define JITTER 1e-4f

// Packed lower-triangular Su: P[i*(i+1)/2 + j], j <= i.
#define PACKED_FLOATS (M_IND * (M_IND + 1) / 2)               // 524800
#define PACKED_BYTES  ((size_t)PACKED_FLOATS * sizeof(float)) // 2,099,200 B

#define TSU 32
#define SU_BLOCKS 528          // 32*33/2 triangular tiles
#define PTS_PER_BLK 128        // 512 blocks, 2/CU resident
#define QSTRIDE 17             // u64 per point row (136 B)
#define GRID_BLKS (N_PTS / PTS_PER_BLK)   // 512
#define SPIN_MAX 32768         // ~5 ms bound; then exact Lu fallback

// R22 ledger:
//  - R21 lesson: balanced-flat su chunks were ~2.5x slower/chunk (lost the
//    prefetch, extra barrier) — the balance was cancelled, worst-block-su
//    theory UNTESTED not refuted. Champion = R13 (kernel 110.4, JSON 163.0).
//  - R22 = exact R13 frame (reg-A p2, early spin, per-tile su WITH prefetch)
//    + ONE variable: 136 heavy tiles (ct>=16) split at chunk 16; second half
//    done by helper block 135-h (reversed pairing: small-main blocks get big
//    extras -> every block's su <= ~18 chunks vs 32). Both halves atomicAdd
//    into memset-zeroed P (atomic path validated R21). Bounded spin + Lu
//    fallback kept (R20-validated insurance).
//  - Spill tripwire: WRITE_SIZE < 10 MB. Neutral-result fork: su not on the
//    crit chain -> next round ablates fused sel+su with p2 stubbed.

// ---------------------------------------------------------------------------
// Su tile k-chunk range [c0,c1) of 32x32 tile (rt,ct), with prefetch.
// atomic=true accumulates via atomicAdd (split tiles); else direct store.
// ---------------------------------------------------------------------------
__device__ __forceinline__ void su_range(const float* __restrict__ Lu_raw,
                                         float* __restrict__ P,
                                         int rt, int ct, int c0, int c1,
                                         bool atomic, int tid,
                                         float (*As)[36], float (*Bs)[36]) {
    int i0 = rt * TSU, j0 = ct * TSU;
    int tx = tid & 15, ty = tid >> 4;
    int sr = tid >> 3, sc = (tid & 7) << 2;
    float a00 = 0.f, a01 = 0.f, a10 = 0.f, a11 = 0.f;

    int gi = i0 + sr, gj = j0 + sr;
    float4 pa = *(const float4*)(Lu_raw + (unsigned)gi * M_IND + (c0 << 5) + sc);
    float4 pb = *(const float4*)(Lu_raw + (unsigned)gj * M_IND + (c0 << 5) + sc);

    for (int c = c0; c < c1; ++c) {
        int gk = (c << 5) + sc;
        float aa[4] = {pa.x, pa.y, pa.z, pa.w};
        float bb[4] = {pb.x, pb.y, pb.z, pb.w};
        #pragma unroll
        for (int q = 0; q < 4; ++q) {
            int k = gk + q;
            aa[q] = (k < gi) ? aa[q] : ((k == gi) ? __expf(aa[q]) : 0.0f);
            bb[q] = (k < gj) ? bb[q] : ((k == gj) ? __expf(bb[q]) : 0.0f);
        }
        *(float4*)&As[sr][sc] = make_float4(aa[0], aa[1], aa[2], aa[3]);
        *(float4*)&Bs[sr][sc] = make_float4(bb[0], bb[1], bb[2], bb[3]);
        __syncthreads();
        if (c + 1 < c1) {
            int kn = ((c + 1) << 5) + sc;
            pa = *(const float4*)(Lu_raw + (unsigned)gi * M_IND + kn);
            pb = *(const float4*)(Lu_raw + (unsigned)gj * M_IND + kn);
        }
        #pragma unroll
        for (int kk = 0; kk < 32; kk += 4) {
            float4 av0 = *(const float4*)&As[ty][kk];
            float4 av1 = *(const float4*)&As[ty + 16][kk];
            float4 bv0 = *(const float4*)&Bs[tx][kk];
            float4 bv1 = *(const float4*)&Bs[tx + 16][kk];
            a00 = fmaf(av0.x, bv0.x, fmaf(av0.y, bv0.y, fmaf(av0.z, bv0.z, fmaf(av0.w, bv0.w, a00))));
            a01 = fmaf(av0.x, bv1.x, fmaf(av0.y, bv1.y, fmaf(av0.z, bv1.z, fmaf(av0.w, bv1.w, a01))));
            a10 = fmaf(av1.x, bv0.x, fmaf(av1.y, bv0.y, fmaf(av1.z, bv0.z, fmaf(av1.w, bv0.w, a10))));
            a11 = fmaf(av1.x, bv1.x, fmaf(av1.y, bv1.y, fmaf(av1.z, bv1.z, fmaf(av1.w, bv1.w, a11))));
        }
        __syncthreads();
    }

    int ia = i0 + ty, ib = i0 + ty + 16;
    int ja = j0 + tx, jb = j0 + tx + 16;
    if (atomic) {
        if (ja <= ia) atomicAdd(&P[((unsigned)ia * (ia + 1) >> 1) + ja], a00);
        if (jb <= ia) atomicAdd(&P[((unsigned)ia * (ia + 1) >> 1) + jb], a01);
        if (ja <= ib) atomicAdd(&P[((unsigned)ib * (ib + 1) >> 1) + ja], a10);
        if (jb <= ib) atomicAdd(&P[((unsigned)ib * (ib + 1) >> 1) + jb], a11);
    } else {
        if (ja <= ia) P[((unsigned)ia * (ia + 1) >> 1) + ja] = a00;
        if (jb <= ia) P[((unsigned)ia * (ia + 1) >> 1) + jb] = a01;
        if (ja <= ib) P[((unsigned)ib * (ib + 1) >> 1) + ja] = a10;
        if (jb <= ib) P[((unsigned)ib * (ib + 1) >> 1) + jb] = a11;
    }
}

// Whole-tile wrapper (standalone su_kernel / MODE 1 path).
__device__ __forceinline__ void su_tile(const float* __restrict__ Lu_raw,
                                        float* __restrict__ P,
                                        int bid, int tid,
                                        float (*As)[36], float (*Bs)[36]) {
    int rt = (int)((sqrtf(8.0f * (float)bid + 1.0f) - 1.0f) * 0.5f);
    while ((rt + 1) * (rt + 2) / 2 <= bid) ++rt;
    while (rt * (rt + 1) / 2 > bid) --rt;
    int ct = bid - rt * (rt + 1) / 2;   // ct <= rt
    su_range(Lu_raw, P, rt, ct, 0, ct + 1, false, tid, As, Bs);
}

__global__ __launch_bounds__(256) void su_kernel(const float* __restrict__ Lu_raw,
                                                 float* __restrict__ P) {
    __shared__ float As[TSU][36];
    __shared__ float Bs[TSU][36];
    su_tile(Lu_raw, P, blockIdx.x, threadIdx.x, As, Bs);
}

// ---------------------------------------------------------------------------
// Sorting-network helpers.
// ---------------------------------------------------------------------------
__device__ __forceinline__ void ce(unsigned long long& x, unsigned long long& y) {
    unsigned long long a = x, b = y;
    bool c = a < b;
    x = c ? a : b;
    y = c ? b : a;
}
__device__ __forceinline__ void ce(float& x, float& y) {
    float a = fminf(x, y), b = fmaxf(x, y);
    x = a; y = b;
}

template <typename KT>
__device__ __forceinline__ void sort16(KT* a) {
    #pragma unroll
    for (int p = 1; p < 16; p <<= 1)
        #pragma unroll
        for (int k = p; k >= 1; k >>= 1)
            #pragma unroll
            for (int j = k & (p - 1); j + k < 16; j += 2 * k)
                #pragma unroll
                for (int i = 0; i < k; ++i)
                    if (i + j + k < 16)
                        if (((i + j) / (2 * p)) == ((i + j + k) / (2 * p)))
                            ce(a[i + j], a[i + j + k]);
}

template <typename KT>
__device__ __forceinline__ void cleanup16(KT* a) {
    #pragma unroll
    for (int d = 8; d >= 1; d >>= 1)
        #pragma unroll
        for (int i = 0; i < 16; ++i)
            if ((i & d) == 0) ce(a[i], a[i | d]);
}

// u-space distance surrogate: u = 0.5*|z|^2 - x.z  (Zs.w holds 0.5*|z|^2).
// d = max(2u + xq, 0) is monotone in u.
__device__ __forceinline__ float uval(float4 z, float xn0, float xn1, float xn2) {
    return fmaf(xn0, z.x, fmaf(xn1, z.y, fmaf(xn2, z.z, z.w)));
}

// ---------------------------------------------------------------------------
// MODE 2: fused (split-balanced su + bounded early ctr spin). MODE 1: P from
// su_kernel. MODE 0: no-workspace exact fallback.
// 512 blocks x 256 thr, 128 pts/blk. Selection: R13-proven (4 subs x 2 pts).
// Phase 2: serial per-thread reg-A (R13-champion).
// LDS: Zs [0,16384) | mus [16384,20480) | qb [20480,37888) |
//      su As/Bs [20480,29696) (MODE 2, dead before selection) |
//      flag [37888,37892).
// ---------------------------------------------------------------------------
template <int MODE>
__global__ __launch_bounds__(256, 2) void vnngp_kernel(const float* __restrict__ X,
                                                       const float* __restrict__ Z,
                                                       const float* __restrict__ mu,
                                                       float* __restrict__ P,
                                                       const float* __restrict__ Lu_raw,
                                                       unsigned int* __restrict__ ctr,
                                                       float* __restrict__ out) {
    __shared__ __align__(16) char smem[37904];
    float4* Zs = (float4*)smem;                                  // 16 KB
    float* mus = (float*)(smem + 16384);                         // 4 KB
    unsigned long long* qb = (unsigned long long*)(smem + 20480); // 17 KB
    int* flagp = (int*)(smem + 37888);
    int tid = threadIdx.x;

    for (int r = tid; r < M_IND; r += 256) {
        float zx = Z[r * 3 + 0], zy = Z[r * 3 + 1], zz = Z[r * 3 + 2];
        Zs[r] = make_float4(zx, zy, zz, 0.5f * (zx * zx + zy * zy + zz * zz));
        mus[r] = mu[r];
    }

    if (MODE == 2) {
        // Split-balanced su. Main map (R13 permutation): block b -> b-th
        // non-cheap tile; blocks 0..15 also do the 16 cheap ct=0 tiles.
        // NEW: tiles with ct>=16 are split at chunk 16; second half done by
        // helper block 135-h (reversed pairing caps every block at ~18
        // chunks). Split-tile halves atomicAdd into memset-zeroed P.
        float (*As)[36] = (float (*)[36])(smem + 20480);
        float (*Bs)[36] = (float (*)[36])(smem + 20480 + 4608);
        int t = blockIdx.x;
        #pragma unroll
        for (int r = 16; r < 32; ++r) {
            int s = (r * (r + 1)) >> 1;
            if (t >= s) ++t;
        }
        int rt = (int)((sqrtf(8.0f * (float)t + 1.0f) - 1.0f) * 0.5f);
        while ((rt + 1) * (rt + 2) / 2 <= t) ++rt;
        while (rt * (rt + 1) / 2 > t) --rt;
        int ct = t - rt * (rt + 1) / 2;
        bool sp = (ct >= 16);
        su_range(Lu_raw, P, rt, ct, 0, sp ? 16 : (ct + 1), sp, tid, As, Bs);
        if (blockIdx.x < 16) {
            int r = 16 + blockIdx.x;               // cheap tile (r,0): 1 chunk
            su_range(Lu_raw, P, r, 0, 0, 1, false, tid, As, Bs);
        }
        if (blockIdx.x < 136) {
            int h = 135 - blockIdx.x;              // reversed pairing
            int rt2 = 16, cum = 0;                 // h-th split tile (id order)
            while (h >= cum + (rt2 - 15)) { cum += (rt2 - 15); ++rt2; }
            int ct2 = 16 + (h - cum);
            su_range(Lu_raw, P, rt2, ct2, 16, ct2 + 1, true, tid, As, Bs);
        }
        __syncthreads();                           // P stores drained
        if (tid == 0) {
            __threadfence();                       // device-scope release
            atomicAdd(ctr, 1u);
        }
    } else {
        __syncthreads();
    }

    {
        int pt = tid >> 2, sub = tid & 3;     // pt 0..63, quad handles pt & pt+64
        int nA = blockIdx.x * PTS_PER_BLK + pt;
        int nB = nA + 64;
        float xA0 = X[nA * 3 + 0], xA1 = X[nA * 3 + 1], xA2 = X[nA * 3 + 2];
        float xB0 = X[nB * 3 + 0], xB1 = X[nB * 3 + 1], xB2 = X[nB * 3 + 2];
        float xqA = fmaf(xA0, xA0, fmaf(xA1, xA1, xA2 * xA2));
        float xqB = fmaf(xB0, xB0, fmaf(xB1, xB1, xB2 * xB2));
        float nA0 = -xA0, nA1 = -xA1, nA2 = -xA2;
        float nB0 = -xB0, nB1 = -xB1, nB2 = -xB2;
        int mbase = sub << 8;
        int rot = sub << 1;   // subs land on disjoint bank quads

        // ---- Pass 1: 16 interleaved class minima per point (u-space) ----
        float TA[16], TB[16];
        #pragma unroll
        for (int j = 0; j < 16; ++j) { TA[j] = 3.4e38f; TB[j] = 3.4e38f; }
        #pragma unroll 1
        for (int c = 0; c < 16; ++c) {
            int base = mbase + (c << 4);
            #pragma unroll
            for (int j = 0; j < 16; ++j) {
                int m = base + ((j + rot) & 15);
                float4 z = Zs[m];
                TA[j] = fminf(TA[j], uval(z, nA0, nA1, nA2));
                TB[j] = fminf(TB[j], uval(z, nB0, nB1, nB2));
            }
        }
        sort16(TA);
        sort16(TB);
        #pragma unroll
        for (int round = 1; round <= 2; round <<= 1) {
            float oA[16], oB[16];
            #pragma unroll
            for (int i = 0; i < 16; ++i) {
                oA[i] = __shfl_xor(TA[i], round, 64);
                oB[i] = __shfl_xor(TB[i], round, 64);
            }
            #pragma unroll
            for (int i = 0; i < 16; ++i) {
                TA[i] = fminf(TA[i], oA[15 - i]);
                TB[i] = fminf(TB[i], oB[15 - i]);
            }
            cleanup16(TA);
            cleanup16(TB);
        }
        float TstarA = TA[15], TstarB = TB[15];   // u-space thresholds

        // ---- Pass 2: collect indices with u <= Tstar (u16, cap 16/sub) ----
        unsigned short* mycA = ((unsigned short*)qb) + pt * (QSTRIDE * 4) + sub * 16;
        unsigned short* mycB = ((unsigned short*)qb) + (pt + 64) * (QSTRIDE * 4) + sub * 16;
        int cntA = 0, cntB = 0;
        #pragma unroll 1
        for (int c = 0; c < 16; ++c) {
            int base = mbase + (c << 4);
            #pragma unroll
            for (int j = 0; j < 16; ++j) {
                int m = base + ((j + rot) & 15);
                float4 z = Zs[m];
                float uA = uval(z, nA0, nA1, nA2);
                float uB = uval(z, nB0, nB1, nB2);
                if (uA <= TstarA) { if (cntA < 16) mycA[cntA] = (unsigned short)m; ++cntA; }
                if (uB <= TstarB) { if (cntB < 16) mycB[cntB] = (unsigned short)m; ++cntB; }
            }
        }

        int ovfA = cntA > 16 ? 1 : 0;
        ovfA |= __shfl_xor(ovfA, 1, 64);
        ovfA |= __shfl_xor(ovfA, 2, 64);
        int ovfB = cntB > 16 ? 1 : 0;
        ovfB |= __shfl_xor(ovfB, 1, 64);
        ovfB |= __shfl_xor(ovfB, 2, 64);

        // ---- finalize point A ----
        if (!ovfA) {
            const unsigned long long* m64 = (const unsigned long long*)mycA;
            unsigned long long raw[4] = {m64[0], m64[1], m64[2], m64[3]};
            unsigned long long C[16];
            #pragma unroll
            for (int i = 0; i < 16; ++i) {
                int m = (int)((raw[i >> 2] >> ((i & 3) * 16)) & 0x3FF);
                float u = uval(Zs[m], nA0, nA1, nA2);
                float d = fmaxf(fmaf(2.0f, u, xqA), 0.0f);
                unsigned long long key =
                    ((unsigned long long)__float_as_uint(d) << 32) | (unsigned)m;
                C[i] = (i < cntA) ? key : ~0ULL;
            }
            sort16(C);
            #pragma unroll
            for (int round = 1; round <= 2; round <<= 1) {
                unsigned long long o[16];
                #pragma unroll
                for (int i = 0; i < 16; ++i) o[i] = __shfl_xor(C[i], round, 64);
                #pragma unroll
                for (int i = 0; i < 16; ++i) {
                    unsigned long long b = o[15 - i];
                    C[i] = C[i] < b ? C[i] : b;
                }
                cleanup16(C);
            }
            if (sub == 0) {
                #pragma unroll
                for (int i = 0; i < 16; ++i) qb[pt * QSTRIDE + i] = C[i];
            }
        } else if (sub == 0) {
            unsigned long long R[16];
            #pragma unroll
            for (int i = 0; i < 16; ++i) R[i] = ~0ULL;
            for (int m = 0; m < M_IND; ++m) {
                float u = uval(Zs[m], nA0, nA1, nA2);
                float d = fmaxf(fmaf(2.0f, u, xqA), 0.0f);
                unsigned long long kk =
                    ((unsigned long long)__float_as_uint(d) << 32) | (unsigned)m;
                if (kk < R[15]) {
                    #pragma unroll
                    for (int j = 0; j < 16; ++j) {
                        unsigned long long t2 = R[j];
                        bool cc = kk < t2;
                        R[j] = cc ? kk : t2;
                        kk = cc ? t2 : kk;
                    }
                }
            }
            #pragma unroll
            for (int i = 0; i < 16; ++i) qb[pt * QSTRIDE + i] = R[i];
        }

        // ---- finalize point B ----
        if (!ovfB) {
            const unsigned long long* m64 = (const unsigned long long*)mycB;
            unsigned long long raw[4] = {m64[0], m64[1], m64[2], m64[3]};
            unsigned long long C[16];
            #pragma unroll
            for (int i = 0; i < 16; ++i) {
                int m = (int)((raw[i >> 2] >> ((i & 3) * 16)) & 0x3FF);
                float u = uval(Zs[m], nB0, nB1, nB2);
                float d = fmaxf(fmaf(2.0f, u, xqB), 0.0f);
                unsigned long long key =
                    ((unsigned long long)__float_as_uint(d) << 32) | (unsigned)m;
                C[i] = (i < cntB) ? key : ~0ULL;
            }
            sort16(C);
            #pragma unroll
            for (int round = 1; round <= 2; round <<= 1) {
                unsigned long long o[16];
                #pragma unroll
                for (int i = 0; i < 16; ++i) o[i] = __shfl_xor(C[i], round, 64);
                #pragma unroll
                for (int i = 0; i < 16; ++i) {
                    unsigned long long b = o[15 - i];
                    C[i] = C[i] < b ? C[i] : b;
                }
                cleanup16(C);
            }
            if (sub == 0) {
                #pragma unroll
                for (int i = 0; i < 16; ++i) qb[(pt + 64) * QSTRIDE + i] = C[i];
            }
        } else if (sub == 0) {
            unsigned long long R[16];
            #pragma unroll
            for (int i = 0; i < 16; ++i) R[i] = ~0ULL;
            for (int m = 0; m < M_IND; ++m) {
                float u = uval(Zs[m], nB0, nB1, nB2);
                float d = fmaxf(fmaf(2.0f, u, xqB), 0.0f);
                unsigned long long kk =
                    ((unsigned long long)__float_as_uint(d) << 32) | (unsigned)m;
                if (kk < R[15]) {
                    #pragma unroll
                    for (int j = 0; j < 16; ++j) {
                        unsigned long long t2 = R[j];
                        bool cc = kk < t2;
                        R[j] = cc ? kk : t2;
                        kk = cc ? t2 : kk;
                    }
                }
            }
            #pragma unroll
            for (int i = 0; i < 16; ++i) qb[(pt + 64) * QSTRIDE + i] = R[i];
        }
    }
    __syncthreads();

    bool havP = (MODE == 1);
    if (MODE == 2) {
        // Early bounded spin (R13 position): selection overlapped all other
        // blocks' su; worst block su now ~18 chunks. Timeout -> Lu fallback.
        if (tid == 0) {
            int ok = 1, iters = 0;
            while (__hip_atomic_load(ctr, __ATOMIC_ACQUIRE, __HIP_MEMORY_SCOPE_AGENT)
                   < (unsigned)GRID_BLKS) {
                __builtin_amdgcn_s_sleep(8);
                if (++iters > SPIN_MAX) { ok = 0; break; }
            }
            *flagp = ok;
        }
        __syncthreads();
        havP = (*flagp != 0);
    }
    if (tid >= PTS_PER_BLK) return;

    // ---- Phase 2: local GP, one thread per point (reg-A, R13-champion) ----
    int n = blockIdx.x * PTS_PER_BLK + tid;
    int idx[KNN];
    float kv[KNN];
    float nx[KNN], ny[KNN], nz[KNN], nq[KNN];
    #pragma unroll
    for (int a = 0; a < KNN; ++a) {
        unsigned long long k = qb[tid * QSTRIDE + a];
        idx[a] = (int)(k & 0xFFFFFFFFULL);
        float d = __uint_as_float((unsigned)(k >> 32));
        kv[a] = __expf(-0.5f * d);            // lKxz entries
        float4 z = Zs[idx[a]];
        nx[a] = z.x; ny[a] = z.y; nz[a] = z.z; nq[a] = z.w;   // nq = 0.5*|z|^2
    }

    // A = lKzz + JITTER*I (lower tri); diag = 1 + 2*JITTER.
    // Off-diag: exp(-0.5*max(sq,0)) = exp(min(dot - nq[r] - nq[c], 0)).
    float A[KNN * (KNN + 1) / 2];
    #pragma unroll
    for (int r = 0; r < KNN; ++r) {
        A[r * (r + 1) / 2 + r] = 1.0f + 2.0f * JITTER;
        #pragma unroll
        for (int c = 0; c < r; ++c) {
            float dot = fmaf(nx[r], nx[c], fmaf(ny[r], ny[c], nz[r] * nz[c]));
            A[r * (r + 1) / 2 + c] = __expf(fminf(dot - nq[r] - nq[c], 0.0f));
        }
    }

    // In-place Cholesky; 1/L[c][c] stored on the diagonal (rsqrt).
    #pragma unroll
    for (int c = 0; c < KNN; ++c) {
        float diag = A[c * (c + 1) / 2 + c];
        #pragma unroll
        for (int k = 0; k < c; ++k) {
            float lv = A[c * (c + 1) / 2 + k];
            diag = fmaf(-lv, lv, diag);
        }
        float rinv = __frsqrt_rn(fmaxf(diag, 1e-12f));
        A[c * (c + 1) / 2 + c] = rinv;
        #pragma unroll
        for (int r = c + 1; r < KNN; ++r) {
            float v = A[r * (r + 1) / 2 + c];
            #pragma unroll
            for (int k = 0; k < c; ++k)
                v = fmaf(-A[r * (r + 1) / 2 + k], A[c * (c + 1) / 2 + k], v);
            A[r * (r + 1) / 2 + c] = v * rinv;
        }
    }

    // Solve A w = kv (forward then backward).
    float w[KNN];
    #pragma unroll
    for (int r = 0; r < KNN; ++r) {
        float v = kv[r];
        #pragma unroll
        for (int c = 0; c < r; ++c) v = fmaf(-A[r * (r + 1) / 2 + c], w[c], v);
        w[r] = v * A[r * (r + 1) / 2 + r];
    }
    #pragma unroll
    for (int r = KNN - 1; r >= 0; --r) {
        float v = w[r];
        #pragma unroll
        for (int c = r + 1; c < KNN; ++c) v = fmaf(-A[c * (c + 1) / 2 + r], w[c], v);
        w[r] = v * A[r * (r + 1) / 2 + r];
    }

    // W lKzz W^T = w.k - JITTER*||w||^2   (A w = k, lKzz = A - JITTER*I)
    float wk = 0.f, ww = 0.f, mean = 0.f;
    #pragma unroll
    for (int a = 0; a < KNN; ++a) {
        wk = fmaf(w[a], kv[a], wk);
        ww = fmaf(w[a], w[a], ww);
        mean = fmaf(w[a], mus[idx[a]], mean);
    }

    // qs = w^T Su[idx,idx] w
    float qs = 0.f;
    if (MODE != 0 && havP) {
        #pragma unroll
        for (int r = 0; r < KNN; ++r) {
            int a = idx[r];
            float wr = w[r];
            float rowacc = 0.f;
            #pragma unroll
            for (int c = 0; c < r; ++c) {
                int b = idx[c];
                int hi = a > b ? a : b;
                int lo = a > b ? b : a;
                rowacc = fmaf(w[c], P[((unsigned)hi * (hi + 1) >> 1) + lo], rowacc);
            }
            qs = fmaf(wr, fmaf(wr, P[((unsigned)a * (a + 1) >> 1) + a], 2.0f * rowacc), qs);
        }
    } else {
        // Exact on-demand: qs = sum_k (sum_a w_a * Lu[idx_a, k])^2
        int si[KNN]; float sw[KNN];
        #pragma unroll
        for (int a = 0; a < KNN; ++a) { si[a] = idx[a]; sw[a] = w[a]; }
        #pragma unroll
        for (int a = 1; a < KNN; ++a) {
            int iv = si[a]; float wv = sw[a];
            int b = a - 1;
            while (b >= 0 && si[b] > iv) { si[b + 1] = si[b]; sw[b + 1] = sw[b]; --b; }
            si[b + 1] = iv; sw[b + 1] = wv;
        }
        int s = 0;
        int kend = si[KNN - 1];
        for (int k = 0; k <= kend; ++k) {
            float v = 0.f;
            if (s < KNN && si[s] == k) {
                v = sw[s] * __expf(Lu_raw[(unsigned)k * M_IND + k]);
                ++s;
            }
            for (int a = s; a < KNN; ++a)
                v = fmaf(sw[a], Lu_raw[(unsigned)si[a] * M_IND + k], v);
            qs = fmaf(v, v, qs);
        }
    }

    float cov = 1.0f - (wk - JITTER * ww) + qs;
    float sd = sqrtf(fmaxf(cov, 0.05f));
    out[n] = mean;
    out[N_PTS + n] = sd;
}

// ---------------------------------------------------------------------------
extern "C" void kernel_launch(void* const* d_in, const int* in_sizes, int n_in,
                              void* d_out, int out_size, void* d_ws, size_t ws_size,
                              hipStream_t stream) {
    const float* X      = (const float*)d_in[0];
    const float* Z      = (const float*)d_in[1];
    const float* Lu_raw = (const float*)d_in[2];
    const float* mu     = (const float*)d_in[3];
    float* out = (float*)d_out;

    if (ws_size >= PACKED_BYTES + 64) {
        // Fused: P (split tiles atomic-accumulate -> zeroed) + counter in d_ws.
        float* P = (float*)d_ws;
        unsigned int* ctr = (unsigned int*)((char*)d_ws + PACKED_BYTES);
        hipMemsetAsync(P, 0, PACKED_BYTES, stream);
        hipMemsetAsync(ctr, 0, sizeof(unsigned int), stream);
        vnngp_kernel<2><<<GRID_BLKS, 256, 0, stream>>>(X, Z, mu, P, Lu_raw, ctr, out);
    } else if (ws_size >= PACKED_BYTES) {
        float* P = (float*)d_ws;
        su_kernel<<<SU_BLOCKS, 256, 0, stream>>>(Lu_raw, P);
        vnngp_kernel<1><<<GRID_BLKS, 256, 0, stream>>>(X, Z, mu, P, Lu_raw, nullptr, out);
    } else {
        vnngp_kernel<0><<<GRID_BLKS, 256, 0, stream>>>(X, Z, mu, nullptr, Lu_raw, nullptr, out);
    }
}